// Round 1
// baseline (368.762 us; speedup 1.0000x reference)
//
#include <hip/hip_runtime.h>

// y[i] = W2[i] . relu(x[i]*W1[i] + b1[i]) + b2[i],  H=8, all fp32.
// Pure streaming, HBM-bound: 104 B in + 4 B out per element.

__global__ __launch_bounds__(256) void tiny_mlp_kernel(
    const float*  __restrict__ x,    // [N]
    const float4* __restrict__ W1,   // [N][8] viewed as [2N] float4
    const float4* __restrict__ b1,   // [N][8] viewed as [2N] float4
    const float4* __restrict__ W2,   // [N][8] viewed as [2N] float4
    const float*  __restrict__ b2,   // [N]
    float*        __restrict__ y,    // [N]
    int n)
{
    const int stride = gridDim.x * blockDim.x;
    for (int i = blockIdx.x * blockDim.x + threadIdx.x; i < n; i += stride) {
        const float xi = x[i];

        const float4 w1a = W1[2 * i];
        const float4 w1b = W1[2 * i + 1];
        const float4 b1a = b1[2 * i];
        const float4 b1b = b1[2 * i + 1];
        const float4 w2a = W2[2 * i];
        const float4 w2b = W2[2 * i + 1];

        // h = relu(x*W1 + b1)
        const float h0 = fmaxf(fmaf(xi, w1a.x, b1a.x), 0.0f);
        const float h1 = fmaxf(fmaf(xi, w1a.y, b1a.y), 0.0f);
        const float h2 = fmaxf(fmaf(xi, w1a.z, b1a.z), 0.0f);
        const float h3 = fmaxf(fmaf(xi, w1a.w, b1a.w), 0.0f);
        const float h4 = fmaxf(fmaf(xi, w1b.x, b1b.x), 0.0f);
        const float h5 = fmaxf(fmaf(xi, w1b.y, b1b.y), 0.0f);
        const float h6 = fmaxf(fmaf(xi, w1b.z, b1b.z), 0.0f);
        const float h7 = fmaxf(fmaf(xi, w1b.w, b1b.w), 0.0f);

        // y = sum(h * W2) + b2  (two 4-term FMA chains, then combine)
        float acc0 = fmaf(h0, w2a.x, b2[i]);
        acc0 = fmaf(h1, w2a.y, acc0);
        acc0 = fmaf(h2, w2a.z, acc0);
        acc0 = fmaf(h3, w2a.w, acc0);
        float acc1 = h4 * w2b.x;
        acc1 = fmaf(h5, w2b.y, acc1);
        acc1 = fmaf(h6, w2b.z, acc1);
        acc1 = fmaf(h7, w2b.w, acc1);

        y[i] = acc0 + acc1;
    }
}

extern "C" void kernel_launch(void* const* d_in, const int* in_sizes, int n_in,
                              void* d_out, int out_size, void* d_ws, size_t ws_size,
                              hipStream_t stream) {
    const float*  x  = (const float*) d_in[0];
    const float4* W1 = (const float4*)d_in[1];
    const float4* b1 = (const float4*)d_in[2];
    const float4* W2 = (const float4*)d_in[3];
    const float*  b2 = (const float*) d_in[4];
    float*        y  = (float*)d_out;

    const int n = in_sizes[0];  // N (x has N elements)

    const int block = 256;
    int grid = (n + block - 1) / block;
    if (grid > 2048) grid = 2048;  // grid-stride the rest

    tiny_mlp_kernel<<<grid, block, 0, stream>>>(x, W1, b1, W2, b2, y, n);
}

// Round 2
// 356.497 us; speedup vs baseline: 1.0344x; 1.0344x over previous
//
#include <hip/hip_runtime.h>

// y[i] = W2[i] . relu(x[i]*W1[i] + b1[i]) + b2[i],  H=8, all fp32.
// Streaming, 104 B in + 4 B out per element.
//
// Coalescing scheme: 2 lanes per element. Lane t owns float4 #t of the
// [N][8] arrays (viewed as [2N] float4), so every dwordx4 load is perfectly
// coalesced (16 B/lane, contiguous across the wave). Pair lanes (t, t^1)
// cover one element; a single shfl_xor combines the two half dot-products.

__global__ __launch_bounds__(256) void tiny_mlp_kernel(
    const float*  __restrict__ x,    // [N]
    const float4* __restrict__ W1v,  // [2N]
    const float4* __restrict__ b1v,  // [2N]
    const float4* __restrict__ W2v,  // [2N]
    const float*  __restrict__ b2,   // [N]
    float*        __restrict__ y,    // [N]
    int n)
{
    const int t = blockIdx.x * blockDim.x + threadIdx.x;  // 2N threads
    if (t >= 2 * n) return;
    const int i = t >> 1;  // element index (pair of lanes shares i)

    const float  xi = x[i];
    const float4 w1 = W1v[t];
    const float4 c1 = b1v[t];
    const float4 w2 = W2v[t];

    // 4 hidden units for this half
    const float h0 = fmaxf(fmaf(xi, w1.x, c1.x), 0.0f);
    const float h1 = fmaxf(fmaf(xi, w1.y, c1.y), 0.0f);
    const float h2 = fmaxf(fmaf(xi, w1.z, c1.z), 0.0f);
    const float h3 = fmaxf(fmaf(xi, w1.w, c1.w), 0.0f);

    // half dot-product
    float p = h0 * w2.x;
    p = fmaf(h1, w2.y, p);
    p = fmaf(h2, w2.z, p);
    p = fmaf(h3, w2.w, p);

    // combine the two halves of the element (lanes t and t^1)
    p += __shfl_xor(p, 1);

    if ((t & 1) == 0) {
        y[i] = p + b2[i];
    }
}

extern "C" void kernel_launch(void* const* d_in, const int* in_sizes, int n_in,
                              void* d_out, int out_size, void* d_ws, size_t ws_size,
                              hipStream_t stream) {
    const float*  x  = (const float*) d_in[0];
    const float4* W1 = (const float4*)d_in[1];
    const float4* b1 = (const float4*)d_in[2];
    const float4* W2 = (const float4*)d_in[3];
    const float*  b2 = (const float*) d_in[4];
    float*        y  = (float*)d_out;

    const int n = in_sizes[0];  // N

    const int block = 256;
    const int threads = 2 * n;                    // 2 lanes per element
    const int grid = (threads + block - 1) / block;

    tiny_mlp_kernel<<<grid, block, 0, stream>>>(x, W1, b1, W2, b2, y, n);
}